// Round 14
// baseline (333.139 us; speedup 1.0000x reference)
//
#include <hip/hip_runtime.h>
#include <math.h>

// Net_19335942767008 round 14: FULL fusion — one block per batch runs the r10
// conv pipeline (4 chunks x 16 samples, same per-wave ILP) with c3 kept in
// LDS, then the r7 256-thread dense tail in-place. 2 launches total. LDS
// regions union by phase (54.8 KB). Math value-identical to r10/r7.

typedef __attribute__((ext_vector_type(8))) short bf16x8;
typedef __attribute__((ext_vector_type(4))) float f32x4;

__device__ __forceinline__ short f2bf(float f) {
  union { float f; unsigned u; } v; v.f = f;
  unsigned r = v.u + 0x7fffu + ((v.u >> 16) & 1u);
  return (short)(r >> 16);
}
__device__ __forceinline__ float bf2f(unsigned short u) {
  union { unsigned u; float f; } v; v.u = ((unsigned)u) << 16;
  return v.f;
}

// ---------- all weight packs (fragment order for convs) ----------
__global__ __launch_bounds__(256) void pack_all(
    const float* __restrict__ w_c1, const float* __restrict__ w_c2,
    const float* __restrict__ w_c3, const float* __restrict__ w_fc,
    const float* __restrict__ w_g1, const float* __restrict__ w_g2,
    short* __restrict__ B1, short* __restrict__ B2, short* __restrict__ B3,
    short* __restrict__ Wfc, short* __restrict__ Wg1, short* __restrict__ Wg2) {
  int idx = blockIdx.x * 256 + threadIdx.x;
  if (idx < 2048) {  // B1f: frag f = nt*2+ks', elem = lane*8+j
    int j = idx & 7, lane = (idx >> 3) & 63, f = idx >> 9;
    int nt = f >> 1, ksp = f & 1;
    int col = lane & 15, quad = lane >> 4;
    int k = ksp * 32 + quad * 8 + j;
    int t = k >> 2, ic = k & 3;
    int oc = nt * 16 + col;
    float v = (t < 9 && ic < 3) ? w_c1[(oc * 3 + ic) * 9 + t] : 0.0f;
    B1[idx] = f2bf(v);
  } else if (idx < 20480) {  // B2f: frag f = nt*9+t
    int i2 = idx - 2048;
    int j = i2 & 7, lane = (i2 >> 3) & 63, f = i2 >> 9;
    int nt = f / 9, t = f - nt * 9;
    int col = lane & 15, quad = lane >> 4;
    int oc = nt * 16 + col, ic = quad * 8 + j;
    B2[i2] = f2bf(w_c2[(oc * 32 + ic) * 9 + t]);
  } else if (idx < 94208) {  // B3f: frag f = ng*18+ks
    int i3 = idx - 20480;
    int j = i3 & 7, lane = (i3 >> 3) & 63, f = i3 >> 9;
    int ng = f / 18, ks = f - ng * 18;
    int col = lane & 15, quad = lane >> 4;
    int oc = ng * 16 + col;
    int k = ks * 32 + quad * 8 + j;
    int t = k >> 6, ic = k & 63;
    B3[i3] = f2bf(w_c3[(oc * 64 + ic) * 9 + t]);
  } else if (idx < 110592) {
    int i = idx - 94208; Wfc[i] = f2bf(w_fc[i]);
  } else if (idx < 126976) {
    int i = idx - 110592; Wg1[i] = f2bf(w_g1[i]);
  } else if (idx < 143360) {
    int i = idx - 126976; Wg2[i] = f2bf(w_g2[i]);
  }
}

// ---------- whole net, one block per batch ----------
__global__ __launch_bounds__(256) void net_fused(
    const float* __restrict__ x, const float* __restrict__ gso,
    const short* __restrict__ B1f, const short* __restrict__ B2f,
    const short* __restrict__ B3f, const short* __restrict__ Wfc,
    const short* __restrict__ Wg1, const short* __restrict__ Wg2,
    const float* __restrict__ b1, const float* __restrict__ g1,
    const float* __restrict__ e1, const float* __restrict__ b2,
    const float* __restrict__ g2, const float* __restrict__ e2,
    const float* __restrict__ b3, const float* __restrict__ g3,
    const float* __restrict__ e3, const float* __restrict__ b_fc,
    const float* __restrict__ b_g1, const float* __restrict__ b_g2,
    const float* __restrict__ w_o, const float* __restrict__ b_o,
    float* __restrict__ out) {
  __shared__ short sBuf[18688];     // conv: frame|sc1|sc2 ; dense: sT|sAhat|sWo|sDinv
  __shared__ short sAct[64 * 136];  // c3 -> activations, persists across stages
  short* sFrame = sBuf;             // 6400 sh
  short* sc1 = sBuf + 6400;         // 8192 sh (16x512, unpadded — r10)
  short* sc2 = sBuf + 14592;        // 4096 sh (16x256, unpadded — r10)
  short* sT = sBuf;                 // 9216 sh (128x72)
  short* sAhat = sBuf + 9216;       // 4608 sh (64x72)
  float* sWo = (float*)(sBuf + 13824);   // 640 f
  float* sDinv = (float*)(sBuf + 15104); // 64 f
  const int tid = threadIdx.x;
  const int b = blockIdx.x;
  const int lane = tid & 63, w = tid >> 6;
  const int col = lane & 15, quad = lane >> 4;
  const int m = lane & 15;

  // ================= conv stage: 4 chunks of 16 samples =================
#pragma unroll 1
  for (int chunk = 0; chunk < 4; ++chunk) {
    const int s0 = b * 64 + chunk * 16;
    // ---- P0: zero + fill 16 padded [10][10][4] bf16 frames ----
    for (int i = tid; i < 800; i += 256)
      *(uint4*)(sFrame + i * 8) = (uint4){0, 0, 0, 0};
    __syncthreads();
#pragma unroll
    for (int it = 0; it < 4; ++it) {
      int p = it * 256 + tid;
      int si = p >> 6, pix = p & 63;
      int y = pix >> 3, xx2 = pix & 7;
      const float* xb = x + (s0 + si) * 192 + pix;
      ushort4 o;
      o.x = (unsigned short)f2bf(xb[0]);
      o.y = (unsigned short)f2bf(xb[64]);
      o.z = (unsigned short)f2bf(xb[128]);
      o.w = 0;
      *(ushort4*)(sFrame + si * 400 + ((y + 1) * 10 + xx2 + 1) * 4) = o;
    }
    __syncthreads();

    // ---- P1: conv1 (wave w -> samples w*4..w*4+3) -> sc1 ----
    {
      bf16x8 Bf[2][2];
#pragma unroll
      for (int nt = 0; nt < 2; ++nt)
#pragma unroll
        for (int ks = 0; ks < 2; ++ks)
          Bf[nt][ks] = *(const bf16x8*)(B1f + ((nt * 2 + ks) << 9) + lane * 8);
      float Abn[2], Cbn[2];
#pragma unroll
      for (int nt = 0; nt < 2; ++nt) {
        int oc = nt * 16 + col;
        float a = g1[oc] * rsqrtf(1.0f + 1e-5f);
        Abn[nt] = a;
        Cbn[nt] = fmaf(b1[oc], a, e1[oc]);
      }
      const int t0 = 2 * quad, t1 = t0 + 1;
      const int ky0 = t0 / 3, kx0 = t0 - 3 * (t0 / 3);
      const int ky1 = t1 / 3, kx1 = t1 - 3 * (t1 / 3);
      const int pl = m >> 2, sub = m & 3;
      const int dy = sub >> 1, dx = sub & 1;
      const uint2 z2 = {0u, 0u};
#pragma unroll
      for (int sl = 0; sl < 4; ++sl) {
        const int si = w * 4 + sl;
        const short* xb = sFrame + si * 400;
#pragma unroll
        for (int tile = 0; tile < 4; ++tile) {
          const int pi = tile * 4 + pl;
          const int py = pi >> 2, px = pi & 3;
          const int cy = 2 * py + dy, cx = 2 * px + dx;
          union { bf16x8 v; uint2 u[2]; } a0, a1;
          a0.u[0] = *(const uint2*)(xb + ((cy + ky0) * 10 + cx + kx0) * 4);
          a0.u[1] = *(const uint2*)(xb + ((cy + ky1) * 10 + cx + kx1) * 4);
          uint2 u8 = *(const uint2*)(xb + ((cy + 2) * 10 + cx + 2) * 4);
          a1.u[0] = (quad == 0) ? u8 : z2;
          a1.u[1] = z2;
          f32x4 acc0 = {0, 0, 0, 0}, acc1 = {0, 0, 0, 0};
          acc0 = __builtin_amdgcn_mfma_f32_16x16x32_bf16(a0.v, Bf[0][0], acc0, 0, 0, 0);
          acc0 = __builtin_amdgcn_mfma_f32_16x16x32_bf16(a1.v, Bf[0][1], acc0, 0, 0, 0);
          acc1 = __builtin_amdgcn_mfma_f32_16x16x32_bf16(a0.v, Bf[1][0], acc1, 0, 0, 0);
          acc1 = __builtin_amdgcn_mfma_f32_16x16x32_bf16(a1.v, Bf[1][1], acc1, 0, 0, 0);
          const int piq = tile * 4 + quad;
#pragma unroll
          for (int nt = 0; nt < 2; ++nt) {
            f32x4 acc = nt ? acc1 : acc0;
            float p0 = fmaf(acc[0], Abn[nt], Cbn[nt]);
            float p1 = fmaf(acc[1], Abn[nt], Cbn[nt]);
            float p2 = fmaf(acc[2], Abn[nt], Cbn[nt]);
            float p3 = fmaf(acc[3], Abn[nt], Cbn[nt]);
            float mx = fmaxf(fmaxf(fmaxf(p0, p1), fmaxf(p2, p3)), 0.0f);
            sc1[si * 512 + piq * 32 + nt * 16 + col] = f2bf(mx);
          }
        }
      }
    }
    __syncthreads();

    // ---- P2: conv2 (wave w -> samples w*4..w*4+3), A from sc1 -> sc2 ----
    {
      bf16x8 Bf[4][9];
#pragma unroll
      for (int nt = 0; nt < 4; ++nt)
#pragma unroll
        for (int t = 0; t < 9; ++t)
          Bf[nt][t] = *(const bf16x8*)(B2f + ((nt * 9 + t) << 9) + lane * 8);
      float Abn[4], Cbn[4];
#pragma unroll
      for (int nt = 0; nt < 4; ++nt) {
        int oc = nt * 16 + col;
        float a = g2[oc] * rsqrtf(1.0f + 1e-5f);
        Abn[nt] = a;
        Cbn[nt] = fmaf(b2[oc], a, e2[oc]);
      }
      const int q2 = m >> 2, sub = m & 3;
      const int cy = 2 * (q2 >> 1) + (sub >> 1);
      const int cx = 2 * (q2 & 1) + (sub & 1);
      int off[9];
      bool valid[9];
#pragma unroll
      for (int t = 0; t < 9; ++t) {
        int ky = t / 3, kx = t - 3 * (t / 3);
        int yy = cy + ky - 1, xx = cx + kx - 1;
        valid[t] = ((unsigned)yy < 4u) && ((unsigned)xx < 4u);
        int yc = min(max(yy, 0), 3), xc = min(max(xx, 0), 3);
        off[t] = (yc * 4 + xc) * 32 + quad * 8;
      }
      const bf16x8 zf = {0, 0, 0, 0, 0, 0, 0, 0};
#pragma unroll
      for (int sl = 0; sl < 4; ++sl) {
        const int si = w * 4 + sl;
        const short* ib = sc1 + si * 512;
        f32x4 acc[4];
#pragma unroll
        for (int nt = 0; nt < 4; ++nt) acc[nt] = (f32x4){0, 0, 0, 0};
#pragma unroll
        for (int t = 0; t < 9; ++t) {
          bf16x8 a = *(const bf16x8*)(ib + off[t]);
          if (!valid[t]) a = zf;
#pragma unroll
          for (int nt = 0; nt < 4; ++nt)
            acc[nt] = __builtin_amdgcn_mfma_f32_16x16x32_bf16(a, Bf[nt][t], acc[nt], 0, 0, 0);
        }
#pragma unroll
        for (int nt = 0; nt < 4; ++nt) {
          float p0 = fmaf(acc[nt][0], Abn[nt], Cbn[nt]);
          float p1 = fmaf(acc[nt][1], Abn[nt], Cbn[nt]);
          float p2 = fmaf(acc[nt][2], Abn[nt], Cbn[nt]);
          float p3 = fmaf(acc[nt][3], Abn[nt], Cbn[nt]);
          float mx = fmaxf(fmaxf(fmaxf(p0, p1), fmaxf(p2, p3)), 0.0f);
          sc2[si * 256 + quad * 64 + nt * 16 + col] = f2bf(mx);
        }
      }
    }
    __syncthreads();

    // ---- P3: conv3, A[18] preloaded, 8 independent accs (r10 ILP) -> sAct ----
    {
      const int cp = m & 3, sl3 = m >> 2;
      const int cy = cp >> 1, cx = cp & 1;
      const short* ib = sc2 + (w * 4 + sl3) * 256;
      bf16x8 A[18];
      const bf16x8 zf = {0, 0, 0, 0, 0, 0, 0, 0};
#pragma unroll
      for (int ks = 0; ks < 18; ++ks) {
        int t = ks >> 1;
        int ky = t / 3, kx = t - 3 * (t / 3);
        int iy = cy + ky - 1, ix = cx + kx - 1;
        bool valid = ((unsigned)iy < 2u) && ((unsigned)ix < 2u);
        int iyc = min(max(iy, 0), 1), ixc = min(max(ix, 0), 1);
        bf16x8 a = *(const bf16x8*)(ib + (iyc * 2 + ixc) * 64 + (ks & 1) * 32 + quad * 8);
        A[ks] = valid ? a : zf;
      }
      f32x4 acc[8];
#pragma unroll
      for (int i = 0; i < 8; ++i) acc[i] = (f32x4){0, 0, 0, 0};
#pragma unroll
      for (int ng = 0; ng < 8; ++ng) {
#pragma unroll
        for (int ks = 0; ks < 18; ++ks) {
          bf16x8 bb = *(const bf16x8*)(B3f + (((ng * 18 + ks) << 6) + lane) * 8);
          acc[ng] = __builtin_amdgcn_mfma_f32_16x16x32_bf16(A[ks], bb, acc[ng], 0, 0, 0);
        }
      }
      const int arow = (chunk * 16 + w * 4 + quad) * 136;
#pragma unroll
      for (int ng = 0; ng < 8; ++ng) {
        int oc = ng * 16 + col;
        float a = g3[oc] * rsqrtf(1.0f + 1e-5f);
        float cc = fmaf(b3[oc], a, e3[oc]);
        float p0 = fmaf(acc[ng][0], a, cc);
        float p1 = fmaf(acc[ng][1], a, cc);
        float p2 = fmaf(acc[ng][2], a, cc);
        float p3 = fmaf(acc[ng][3], a, cc);
        float mx = fmaxf(fmaxf(fmaxf(p0, p1), fmaxf(p2, p3)), 0.0f);
        sAct[arow + oc] = f2bf(mx);
      }
    }
    __syncthreads();
  }

  // ================= dense stage (r7 256-thread tail, in-place) =================
  float* sG = (float*)sT;
  for (int i = tid; i < 4096; i += 256) sG[i] = gso[b * 4096 + i];
  for (int i = tid; i < 640; i += 256) sWo[i] = w_o[i];
  __syncthreads();
  if (tid < 64) {
    float ssum = 1.0f;
    for (int j = 0; j < 64; ++j) ssum += sG[j * 64 + tid];
    sDinv[tid] = rsqrtf(ssum);
  }
  __syncthreads();
  for (int i = tid; i < 4096; i += 256) {
    int r = i >> 6, c = i & 63;
    float v = sDinv[r] * (sG[i] + (r == c ? 1.0f : 0.0f)) * sDinv[c];
    sAhat[r * 72 + c] = f2bf(v);
  }
  __syncthreads();
  const int arow = (w * 16 + col) * 136;
  const int crow0 = (w * 16 + quad * 4) * 136;
  bf16x8 A[4];
  f32x4 acc[8];

  // ---- FC ----
#pragma unroll
  for (int ks = 0; ks < 4; ++ks)
    A[ks] = *(const bf16x8*)(sAct + arow + ks * 32 + quad * 8);
  __syncthreads();
#pragma unroll
  for (int i = 0; i < 8; ++i) acc[i] = (f32x4){0, 0, 0, 0};
#pragma unroll
  for (int nt = 0; nt < 8; ++nt) {
    const int n = nt * 16 + col;
#pragma unroll
    for (int ks = 0; ks < 4; ++ks) {
      bf16x8 bb = *(const bf16x8*)(Wfc + n * 128 + ks * 32 + quad * 8);
      acc[nt] = __builtin_amdgcn_mfma_f32_16x16x32_bf16(A[ks], bb, acc[nt], 0, 0, 0);
    }
  }
#pragma unroll
  for (int nt = 0; nt < 8; ++nt) {
    const int n = nt * 16 + col;
    const float bv = b_fc[n];
#pragma unroll
    for (int reg = 0; reg < 4; ++reg)
      sAct[crow0 + reg * 136 + n] = f2bf(fmaxf(acc[nt][reg] + bv, 0.0f));
  }
  __syncthreads();

  // ---- G1 -> sT (transposed) ----
#pragma unroll
  for (int ks = 0; ks < 4; ++ks)
    A[ks] = *(const bf16x8*)(sAct + arow + ks * 32 + quad * 8);
  __syncthreads();  // all reads of sG done; sT overwrite safe
#pragma unroll
  for (int i = 0; i < 8; ++i) acc[i] = (f32x4){0, 0, 0, 0};
#pragma unroll
  for (int nt = 0; nt < 8; ++nt) {
    const int n = nt * 16 + col;
#pragma unroll
    for (int ks = 0; ks < 4; ++ks) {
      bf16x8 bb = *(const bf16x8*)(Wg1 + n * 128 + ks * 32 + quad * 8);
      acc[nt] = __builtin_amdgcn_mfma_f32_16x16x32_bf16(A[ks], bb, acc[nt], 0, 0, 0);
    }
  }
#pragma unroll
  for (int nt = 0; nt < 8; ++nt) {
    const int n = nt * 16 + col;
    ushort4 pk;
    pk.x = (unsigned short)f2bf(acc[nt][0]);
    pk.y = (unsigned short)f2bf(acc[nt][1]);
    pk.z = (unsigned short)f2bf(acc[nt][2]);
    pk.w = (unsigned short)f2bf(acc[nt][3]);
    *(ushort4*)(sT + n * 72 + w * 16 + quad * 4) = pk;
  }
  __syncthreads();

  // ---- AGG1 ----
  bf16x8 Ah[2];
#pragma unroll
  for (int ks = 0; ks < 2; ++ks)
    Ah[ks] = *(const bf16x8*)(sAhat + (w * 16 + col) * 72 + ks * 32 + quad * 8);
#pragma unroll
  for (int i = 0; i < 8; ++i) acc[i] = (f32x4){0, 0, 0, 0};
#pragma unroll
  for (int nt = 0; nt < 8; ++nt) {
    const int n = nt * 16 + col;
#pragma unroll
    for (int ks = 0; ks < 2; ++ks) {
      bf16x8 bb = *(const bf16x8*)(sT + n * 72 + ks * 32 + quad * 8);
      acc[nt] = __builtin_amdgcn_mfma_f32_16x16x32_bf16(Ah[ks], bb, acc[nt], 0, 0, 0);
    }
  }
#pragma unroll
  for (int nt = 0; nt < 8; ++nt) {
    const int n = nt * 16 + col;
    const float bv = b_g1[n];
#pragma unroll
    for (int reg = 0; reg < 4; ++reg)
      sAct[crow0 + reg * 136 + n] = f2bf(fmaxf(acc[nt][reg] + bv, 0.0f));
  }
  __syncthreads();

  // ---- G2 -> sT ----
#pragma unroll
  for (int ks = 0; ks < 4; ++ks)
    A[ks] = *(const bf16x8*)(sAct + arow + ks * 32 + quad * 8);
  __syncthreads();
#pragma unroll
  for (int i = 0; i < 8; ++i) acc[i] = (f32x4){0, 0, 0, 0};
#pragma unroll
  for (int nt = 0; nt < 8; ++nt) {
    const int n = nt * 16 + col;
#pragma unroll
    for (int ks = 0; ks < 4; ++ks) {
      bf16x8 bb = *(const bf16x8*)(Wg2 + n * 128 + ks * 32 + quad * 8);
      acc[nt] = __builtin_amdgcn_mfma_f32_16x16x32_bf16(A[ks], bb, acc[nt], 0, 0, 0);
    }
  }
#pragma unroll
  for (int nt = 0; nt < 8; ++nt) {
    const int n = nt * 16 + col;
    ushort4 pk;
    pk.x = (unsigned short)f2bf(acc[nt][0]);
    pk.y = (unsigned short)f2bf(acc[nt][1]);
    pk.z = (unsigned short)f2bf(acc[nt][2]);
    pk.w = (unsigned short)f2bf(acc[nt][3]);
    *(ushort4*)(sT + n * 72 + w * 16 + quad * 4) = pk;
  }
  __syncthreads();

  // ---- AGG2 ----
#pragma unroll
  for (int i = 0; i < 8; ++i) acc[i] = (f32x4){0, 0, 0, 0};
#pragma unroll
  for (int nt = 0; nt < 8; ++nt) {
    const int n = nt * 16 + col;
#pragma unroll
    for (int ks = 0; ks < 2; ++ks) {
      bf16x8 bb = *(const bf16x8*)(sT + n * 72 + ks * 32 + quad * 8);
      acc[nt] = __builtin_amdgcn_mfma_f32_16x16x32_bf16(Ah[ks], bb, acc[nt], 0, 0, 0);
    }
  }
#pragma unroll
  for (int nt = 0; nt < 8; ++nt) {
    const int n = nt * 16 + col;
    const float bv = b_g2[n];
#pragma unroll
    for (int reg = 0; reg < 4; ++reg)
      sAct[crow0 + reg * 136 + n] = f2bf(fmaxf(acc[nt][reg] + bv, 0.0f));
  }
  __syncthreads();

  // ---- HEAD ----
  {
    const int j = tid >> 2, o = tid & 3;
    float a0 = 0.0f;
#pragma unroll
    for (int k8 = 0; k8 < 16; ++k8) {
      union { bf16x8 v; unsigned short u[8]; } h;
      h.v = *(const bf16x8*)(sAct + j * 136 + k8 * 8);
#pragma unroll
      for (int jj = 0; jj < 8; ++jj)
        a0 = fmaf(bf2f(h.u[jj]), sWo[o * 128 + k8 * 8 + jj], a0);
    }
    out[(b * 64 + j) * 5 + o] = a0 + b_o[o];
    if (tid < 64) {
      float a4 = 0.0f;
#pragma unroll
      for (int k8 = 0; k8 < 16; ++k8) {
        union { bf16x8 v; unsigned short u[8]; } h;
        h.v = *(const bf16x8*)(sAct + tid * 136 + k8 * 8);
#pragma unroll
        for (int jj = 0; jj < 8; ++jj)
          a4 = fmaf(bf2f(h.u[jj]), sWo[512 + k8 * 8 + jj], a4);
      }
      out[(b * 64 + tid) * 5 + 4] = a4 + b_o[4];
    }
  }
}

extern "C" void kernel_launch(void* const* d_in, const int* in_sizes, int n_in,
                              void* d_out, int out_size, void* d_ws, size_t ws_size,
                              hipStream_t stream) {
  const float* x    = (const float*)d_in[0];
  const float* gso  = (const float*)d_in[1];
  const float* w_c1 = (const float*)d_in[2];
  const float* b_c1 = (const float*)d_in[3];
  const float* g_b1 = (const float*)d_in[4];
  const float* e_b1 = (const float*)d_in[5];
  const float* w_c2 = (const float*)d_in[6];
  const float* b_c2 = (const float*)d_in[7];
  const float* g_b2 = (const float*)d_in[8];
  const float* e_b2 = (const float*)d_in[9];
  const float* w_c3 = (const float*)d_in[10];
  const float* b_c3 = (const float*)d_in[11];
  const float* g_b3 = (const float*)d_in[12];
  const float* e_b3 = (const float*)d_in[13];
  const float* w_fc = (const float*)d_in[14];
  const float* b_fc = (const float*)d_in[15];
  const float* w_g1 = (const float*)d_in[16];
  const float* b_g1 = (const float*)d_in[17];
  const float* w_g2 = (const float*)d_in[18];
  const float* b_g2 = (const float*)d_in[19];
  const float* w_o  = (const float*)d_in[20];
  const float* b_o  = (const float*)d_in[21];
  float* out = (float*)d_out;
  char* ws = (char*)d_ws;

  // workspace: packed weights only, NO aliasing, total 286,720 B
  short* B1  = (short*)(ws + 0);        //   4,096 (fragment order)
  short* B2  = (short*)(ws + 4096);     //  36,864 (fragment order)
  short* B3  = (short*)(ws + 40960);    // 147,456 (fragment order)
  short* Wfc = (short*)(ws + 188416);   //  32,768
  short* Wg1 = (short*)(ws + 221184);   //  32,768
  short* Wg2 = (short*)(ws + 253952);   //  32,768

  pack_all<<<560, 256, 0, stream>>>(w_c1, w_c2, w_c3, w_fc, w_g1, w_g2,
                                    B1, B2, B3, Wfc, Wg1, Wg2);
  net_fused<<<256, 256, 0, stream>>>(x, gso, B1, B2, B3, Wfc, Wg1, Wg2,
                                     b_c1, g_b1, e_b1, b_c2, g_b2, e_b2,
                                     b_c3, g_b3, e_b3, b_fc, b_g1, b_g2,
                                     w_o, b_o, out);
}

// Round 15
// 157.797 us; speedup vs baseline: 2.1112x; 2.1112x over previous
//
#include <hip/hip_runtime.h>
#include <math.h>

// Net_19335942767008 round 15: REVERT to round 10 exactly — the measured
// optimum (155.9 us). r11-r14 variations (occupancy pushes, padding, full
// fusion) all regressed; r10's structure: 3 launches, 16-sample conv blocks,
// P3 with 8 independent acc chains + A[18] preload (per-wave ILP), fragment-
// order weights read from global (L1/L2 broadcast), unpadded LDS (contiguous
// wave reads = conflict-free), 512-thread per-batch dense tail.

typedef __attribute__((ext_vector_type(8))) short bf16x8;
typedef __attribute__((ext_vector_type(4))) float f32x4;

__device__ __forceinline__ short f2bf(float f) {
  union { float f; unsigned u; } v; v.f = f;
  unsigned r = v.u + 0x7fffu + ((v.u >> 16) & 1u);
  return (short)(r >> 16);
}
__device__ __forceinline__ float bf2f(unsigned short u) {
  union { unsigned u; float f; } v; v.u = ((unsigned)u) << 16;
  return v.f;
}

// ---------- all weight packs (fragment order for convs) ----------
__global__ __launch_bounds__(256) void pack_all(
    const float* __restrict__ w_c1, const float* __restrict__ w_c2,
    const float* __restrict__ w_c3, const float* __restrict__ w_fc,
    const float* __restrict__ w_g1, const float* __restrict__ w_g2,
    short* __restrict__ B1, short* __restrict__ B2, short* __restrict__ B3,
    short* __restrict__ Wfc, short* __restrict__ Wg1, short* __restrict__ Wg2) {
  int idx = blockIdx.x * 256 + threadIdx.x;
  if (idx < 2048) {  // B1f: frag f = nt*2+ks', elem = lane*8+j
    int j = idx & 7, lane = (idx >> 3) & 63, f = idx >> 9;
    int nt = f >> 1, ksp = f & 1;
    int col = lane & 15, quad = lane >> 4;
    int k = ksp * 32 + quad * 8 + j;
    int t = k >> 2, ic = k & 3;
    int oc = nt * 16 + col;
    float v = (t < 9 && ic < 3) ? w_c1[(oc * 3 + ic) * 9 + t] : 0.0f;
    B1[idx] = f2bf(v);
  } else if (idx < 20480) {  // B2f: frag f = nt*9+t
    int i2 = idx - 2048;
    int j = i2 & 7, lane = (i2 >> 3) & 63, f = i2 >> 9;
    int nt = f / 9, t = f - nt * 9;
    int col = lane & 15, quad = lane >> 4;
    int oc = nt * 16 + col, ic = quad * 8 + j;
    B2[i2] = f2bf(w_c2[(oc * 32 + ic) * 9 + t]);
  } else if (idx < 94208) {  // B3f: frag f = ng*18+ks
    int i3 = idx - 20480;
    int j = i3 & 7, lane = (i3 >> 3) & 63, f = i3 >> 9;
    int ng = f / 18, ks = f - ng * 18;
    int col = lane & 15, quad = lane >> 4;
    int oc = ng * 16 + col;
    int k = ks * 32 + quad * 8 + j;
    int t = k >> 6, ic = k & 63;
    B3[i3] = f2bf(w_c3[(oc * 64 + ic) * 9 + t]);
  } else if (idx < 110592) {
    int i = idx - 94208; Wfc[i] = f2bf(w_fc[i]);
  } else if (idx < 126976) {
    int i = idx - 110592; Wg1[i] = f2bf(w_g1[i]);
  } else if (idx < 143360) {
    int i = idx - 126976; Wg2[i] = f2bf(w_g2[i]);
  }
}

// ---------- fused conv stack: x [S,3,8,8] -> c3 [S,128] bf16 ----------
__global__ __launch_bounds__(256, 2) void conv_all(
    const float* __restrict__ x, const short* __restrict__ B1f,
    const short* __restrict__ B2f, const short* __restrict__ B3f,
    const float* __restrict__ b1, const float* __restrict__ g1,
    const float* __restrict__ e1, const float* __restrict__ b2,
    const float* __restrict__ g2, const float* __restrict__ e2,
    const float* __restrict__ b3, const float* __restrict__ g3,
    const float* __restrict__ e3, short* __restrict__ c3) {
  __shared__ short sFrame[16 * 400];  // padded input frames, 12.8 KB
  __shared__ short sc1[16 * 512];     // conv1 out, unpadded, 16 KB
  __shared__ short sc2[16 * 256];     // conv2 out, unpadded, 8 KB
  const int tid = threadIdx.x;
  const int s0 = blockIdx.x * 16;
  const int lane = tid & 63, w = tid >> 6;
  const int col = lane & 15, quad = lane >> 4;
  const int m = lane & 15;

  // ---- P0: zero + fill 16 padded [10][10][4] bf16 frames ----
  for (int i = tid; i < 800; i += 256)
    *(uint4*)(sFrame + i * 8) = (uint4){0, 0, 0, 0};
  __syncthreads();
#pragma unroll
  for (int it = 0; it < 4; ++it) {
    int p = it * 256 + tid;
    int si = p >> 6, pix = p & 63;
    int y = pix >> 3, xx2 = pix & 7;
    const float* xb = x + (s0 + si) * 192 + pix;
    ushort4 o;
    o.x = (unsigned short)f2bf(xb[0]);
    o.y = (unsigned short)f2bf(xb[64]);
    o.z = (unsigned short)f2bf(xb[128]);
    o.w = 0;
    *(ushort4*)(sFrame + si * 400 + ((y + 1) * 10 + xx2 + 1) * 4) = o;
  }
  __syncthreads();

  // ---- P1: conv1 (wave w -> samples w*4..w*4+3) -> sc1 ----
  {
    bf16x8 Bf[2][2];
#pragma unroll
    for (int nt = 0; nt < 2; ++nt)
#pragma unroll
      for (int ks = 0; ks < 2; ++ks)
        Bf[nt][ks] = *(const bf16x8*)(B1f + ((nt * 2 + ks) << 9) + lane * 8);
    float Abn[2], Cbn[2];
#pragma unroll
    for (int nt = 0; nt < 2; ++nt) {
      int oc = nt * 16 + col;
      float a = g1[oc] * rsqrtf(1.0f + 1e-5f);
      Abn[nt] = a;
      Cbn[nt] = fmaf(b1[oc], a, e1[oc]);
    }
    const int t0 = 2 * quad, t1 = t0 + 1;
    const int ky0 = t0 / 3, kx0 = t0 - 3 * (t0 / 3);
    const int ky1 = t1 / 3, kx1 = t1 - 3 * (t1 / 3);
    const int pl = m >> 2, sub = m & 3;
    const int dy = sub >> 1, dx = sub & 1;
    const uint2 z2 = {0u, 0u};
#pragma unroll
    for (int sl = 0; sl < 4; ++sl) {
      const int si = w * 4 + sl;
      const short* xb = sFrame + si * 400;
#pragma unroll
      for (int tile = 0; tile < 4; ++tile) {
        const int pi = tile * 4 + pl;
        const int py = pi >> 2, px = pi & 3;
        const int cy = 2 * py + dy, cx = 2 * px + dx;
        union { bf16x8 v; uint2 u[2]; } a0, a1;
        a0.u[0] = *(const uint2*)(xb + ((cy + ky0) * 10 + cx + kx0) * 4);
        a0.u[1] = *(const uint2*)(xb + ((cy + ky1) * 10 + cx + kx1) * 4);
        uint2 u8 = *(const uint2*)(xb + ((cy + 2) * 10 + cx + 2) * 4);
        a1.u[0] = (quad == 0) ? u8 : z2;
        a1.u[1] = z2;
        f32x4 acc0 = {0, 0, 0, 0}, acc1 = {0, 0, 0, 0};
        acc0 = __builtin_amdgcn_mfma_f32_16x16x32_bf16(a0.v, Bf[0][0], acc0, 0, 0, 0);
        acc0 = __builtin_amdgcn_mfma_f32_16x16x32_bf16(a1.v, Bf[0][1], acc0, 0, 0, 0);
        acc1 = __builtin_amdgcn_mfma_f32_16x16x32_bf16(a0.v, Bf[1][0], acc1, 0, 0, 0);
        acc1 = __builtin_amdgcn_mfma_f32_16x16x32_bf16(a1.v, Bf[1][1], acc1, 0, 0, 0);
        const int piq = tile * 4 + quad;
#pragma unroll
        for (int nt = 0; nt < 2; ++nt) {
          f32x4 acc = nt ? acc1 : acc0;
          float p0 = fmaf(acc[0], Abn[nt], Cbn[nt]);
          float p1 = fmaf(acc[1], Abn[nt], Cbn[nt]);
          float p2 = fmaf(acc[2], Abn[nt], Cbn[nt]);
          float p3 = fmaf(acc[3], Abn[nt], Cbn[nt]);
          float mx = fmaxf(fmaxf(fmaxf(p0, p1), fmaxf(p2, p3)), 0.0f);
          sc1[si * 512 + piq * 32 + nt * 16 + col] = f2bf(mx);
        }
      }
    }
  }
  __syncthreads();

  // ---- P2: conv2 (wave w -> samples w*4..w*4+3), A from sc1 -> sc2 ----
  {
    bf16x8 Bf[4][9];
#pragma unroll
    for (int nt = 0; nt < 4; ++nt)
#pragma unroll
      for (int t = 0; t < 9; ++t)
        Bf[nt][t] = *(const bf16x8*)(B2f + ((nt * 9 + t) << 9) + lane * 8);
    float Abn[4], Cbn[4];
#pragma unroll
    for (int nt = 0; nt < 4; ++nt) {
      int oc = nt * 16 + col;
      float a = g2[oc] * rsqrtf(1.0f + 1e-5f);
      Abn[nt] = a;
      Cbn[nt] = fmaf(b2[oc], a, e2[oc]);
    }
    const int q2 = m >> 2, sub = m & 3;
    const int cy = 2 * (q2 >> 1) + (sub >> 1);
    const int cx = 2 * (q2 & 1) + (sub & 1);
    int off[9];
    bool valid[9];
#pragma unroll
    for (int t = 0; t < 9; ++t) {
      int ky = t / 3, kx = t - 3 * (t / 3);
      int yy = cy + ky - 1, xx = cx + kx - 1;
      valid[t] = ((unsigned)yy < 4u) && ((unsigned)xx < 4u);
      int yc = min(max(yy, 0), 3), xc = min(max(xx, 0), 3);
      off[t] = (yc * 4 + xc) * 32 + quad * 8;
    }
    const bf16x8 zf = {0, 0, 0, 0, 0, 0, 0, 0};
#pragma unroll
    for (int sl = 0; sl < 4; ++sl) {
      const int si = w * 4 + sl;
      const short* ib = sc1 + si * 512;
      f32x4 acc[4];
#pragma unroll
      for (int nt = 0; nt < 4; ++nt) acc[nt] = (f32x4){0, 0, 0, 0};
#pragma unroll
      for (int t = 0; t < 9; ++t) {
        bf16x8 a = *(const bf16x8*)(ib + off[t]);
        if (!valid[t]) a = zf;
#pragma unroll
        for (int nt = 0; nt < 4; ++nt)
          acc[nt] = __builtin_amdgcn_mfma_f32_16x16x32_bf16(a, Bf[nt][t], acc[nt], 0, 0, 0);
      }
#pragma unroll
      for (int nt = 0; nt < 4; ++nt) {
        float p0 = fmaf(acc[nt][0], Abn[nt], Cbn[nt]);
        float p1 = fmaf(acc[nt][1], Abn[nt], Cbn[nt]);
        float p2 = fmaf(acc[nt][2], Abn[nt], Cbn[nt]);
        float p3 = fmaf(acc[nt][3], Abn[nt], Cbn[nt]);
        float mx = fmaxf(fmaxf(fmaxf(p0, p1), fmaxf(p2, p3)), 0.0f);
        sc2[si * 256 + quad * 64 + nt * 16 + col] = f2bf(mx);
      }
    }
  }
  __syncthreads();

  // ---- P3: conv3, A from sc2, B fragments direct from global (L1) ----
  {
    const int cp = m & 3, sl3 = m >> 2;
    const int cy = cp >> 1, cx = cp & 1;
    const short* ib = sc2 + (w * 4 + sl3) * 256;
    bf16x8 A[18];
    const bf16x8 zf = {0, 0, 0, 0, 0, 0, 0, 0};
#pragma unroll
    for (int ks = 0; ks < 18; ++ks) {
      int t = ks >> 1;
      int ky = t / 3, kx = t - 3 * (t / 3);
      int iy = cy + ky - 1, ix = cx + kx - 1;
      bool valid = ((unsigned)iy < 2u) && ((unsigned)ix < 2u);
      int iyc = min(max(iy, 0), 1), ixc = min(max(ix, 0), 1);
      bf16x8 a = *(const bf16x8*)(ib + (iyc * 2 + ixc) * 64 + (ks & 1) * 32 + quad * 8);
      A[ks] = valid ? a : zf;
    }
    f32x4 acc[8];
#pragma unroll
    for (int i = 0; i < 8; ++i) acc[i] = (f32x4){0, 0, 0, 0};
#pragma unroll
    for (int ng = 0; ng < 8; ++ng) {
#pragma unroll
      for (int ks = 0; ks < 18; ++ks) {
        bf16x8 b = *(const bf16x8*)(B3f + (((ng * 18 + ks) << 6) + lane) * 8);
        acc[ng] = __builtin_amdgcn_mfma_f32_16x16x32_bf16(A[ks], b, acc[ng], 0, 0, 0);
      }
    }
    const int sample = s0 + w * 4 + quad;
#pragma unroll
    for (int ng = 0; ng < 8; ++ng) {
      int oc = ng * 16 + col;
      float a = g3[oc] * rsqrtf(1.0f + 1e-5f);
      float cc = fmaf(b3[oc], a, e3[oc]);
      float p0 = fmaf(acc[ng][0], a, cc);
      float p1 = fmaf(acc[ng][1], a, cc);
      float p2 = fmaf(acc[ng][2], a, cc);
      float p3 = fmaf(acc[ng][3], a, cc);
      float mx = fmaxf(fmaxf(fmaxf(p0, p1), fmaxf(p2, p3)), 0.0f);
      c3[sample * 128 + oc] = f2bf(mx);
    }
  }
}

// ---------- fused dense tail: one block (512 thr, 8 waves) per batch ----------
__global__ __launch_bounds__(512) void fused_dense(
    const short* __restrict__ c3, const float* __restrict__ gso,
    const short* __restrict__ Wfc, const short* __restrict__ Wg1,
    const short* __restrict__ Wg2, const float* __restrict__ b_fc,
    const float* __restrict__ b_g1, const float* __restrict__ b_g2,
    const float* __restrict__ w_o, const float* __restrict__ b_o,
    float* __restrict__ out) {
  __shared__ short sAct[64 * 136];
  __shared__ short sT[128 * 72];
  __shared__ short sAhat[64 * 72];
  __shared__ float sDinv[64];
  __shared__ float sWo[640];
  const int tid = threadIdx.x;
  const int b = blockIdx.x;
  float* sG = (float*)sT;
  for (int i = tid; i < 4096; i += 512) sG[i] = gso[b * 4096 + i];
  for (int i = tid; i < 640; i += 512) sWo[i] = w_o[i];
  __syncthreads();
  if (tid < 64) {
    float ssum = 1.0f;
    for (int j = 0; j < 64; ++j) ssum += sG[j * 64 + tid];
    sDinv[tid] = rsqrtf(ssum);
  }
  __syncthreads();
  for (int i = tid; i < 4096; i += 512) {
    int r = i >> 6, c = i & 63;
    float v = sDinv[r] * (sG[i] + (r == c ? 1.0f : 0.0f)) * sDinv[c];
    sAhat[r * 72 + c] = f2bf(v);
  }
  for (int i = tid; i < 1024; i += 512) {
    int r = i >> 4, seg = i & 15;
    *(bf16x8*)(sAct + r * 136 + seg * 8) =
        *(const bf16x8*)(c3 + (b * 64 + r) * 128 + seg * 8);
  }
  __syncthreads();
  const int lane = tid & 63, w8 = tid >> 6;
  const int rg = w8 >> 1, nh = w8 & 1;
  const int col = lane & 15, quad = lane >> 4;
  const int arow = (rg * 16 + col) * 136;
  const int crow0 = (rg * 16 + quad * 4) * 136;
  bf16x8 A[4];
  f32x4 acc[4];

  // ---- FC ----
#pragma unroll
  for (int ks = 0; ks < 4; ++ks)
    A[ks] = *(const bf16x8*)(sAct + arow + ks * 32 + quad * 8);
  __syncthreads();
#pragma unroll
  for (int i = 0; i < 4; ++i) acc[i] = (f32x4){0, 0, 0, 0};
#pragma unroll
  for (int ntl = 0; ntl < 4; ++ntl) {
    const int n = (nh * 4 + ntl) * 16 + col;
#pragma unroll
    for (int ks = 0; ks < 4; ++ks) {
      bf16x8 bb = *(const bf16x8*)(Wfc + n * 128 + ks * 32 + quad * 8);
      acc[ntl] = __builtin_amdgcn_mfma_f32_16x16x32_bf16(A[ks], bb, acc[ntl], 0, 0, 0);
    }
  }
#pragma unroll
  for (int ntl = 0; ntl < 4; ++ntl) {
    const int n = (nh * 4 + ntl) * 16 + col;
    const float bv = b_fc[n];
#pragma unroll
    for (int reg = 0; reg < 4; ++reg)
      sAct[crow0 + reg * 136 + n] = f2bf(fmaxf(acc[ntl][reg] + bv, 0.0f));
  }
  __syncthreads();

  // ---- G1 -> sT (transposed) ----
#pragma unroll
  for (int ks = 0; ks < 4; ++ks)
    A[ks] = *(const bf16x8*)(sAct + arow + ks * 32 + quad * 8);
#pragma unroll
  for (int i = 0; i < 4; ++i) acc[i] = (f32x4){0, 0, 0, 0};
#pragma unroll
  for (int ntl = 0; ntl < 4; ++ntl) {
    const int n = (nh * 4 + ntl) * 16 + col;
#pragma unroll
    for (int ks = 0; ks < 4; ++ks) {
      bf16x8 bb = *(const bf16x8*)(Wg1 + n * 128 + ks * 32 + quad * 8);
      acc[ntl] = __builtin_amdgcn_mfma_f32_16x16x32_bf16(A[ks], bb, acc[ntl], 0, 0, 0);
    }
  }
#pragma unroll
  for (int ntl = 0; ntl < 4; ++ntl) {
    const int n = (nh * 4 + ntl) * 16 + col;
    ushort4 pk;
    pk.x = (unsigned short)f2bf(acc[ntl][0]);
    pk.y = (unsigned short)f2bf(acc[ntl][1]);
    pk.z = (unsigned short)f2bf(acc[ntl][2]);
    pk.w = (unsigned short)f2bf(acc[ntl][3]);
    *(ushort4*)(sT + n * 72 + rg * 16 + quad * 4) = pk;
  }
  __syncthreads();

  // ---- AGG1 ----
  bf16x8 Ah[2];
#pragma unroll
  for (int ks = 0; ks < 2; ++ks)
    Ah[ks] = *(const bf16x8*)(sAhat + (rg * 16 + col) * 72 + ks * 32 + quad * 8);
#pragma unroll
  for (int i = 0; i < 4; ++i) acc[i] = (f32x4){0, 0, 0, 0};
#pragma unroll
  for (int ntl = 0; ntl < 4; ++ntl) {
    const int n = (nh * 4 + ntl) * 16 + col;
#pragma unroll
    for (int ks = 0; ks < 2; ++ks) {
      bf16x8 bb = *(const bf16x8*)(sT + n * 72 + ks * 32 + quad * 8);
      acc[ntl] = __builtin_amdgcn_mfma_f32_16x16x32_bf16(Ah[ks], bb, acc[ntl], 0, 0, 0);
    }
  }
#pragma unroll
  for (int ntl = 0; ntl < 4; ++ntl) {
    const int n = (nh * 4 + ntl) * 16 + col;
    const float bv = b_g1[n];
#pragma unroll
    for (int reg = 0; reg < 4; ++reg)
      sAct[crow0 + reg * 136 + n] = f2bf(fmaxf(acc[ntl][reg] + bv, 0.0f));
  }
  __syncthreads();

  // ---- G2 -> sT ----
#pragma unroll
  for (int ks = 0; ks < 4; ++ks)
    A[ks] = *(const bf16x8*)(sAct + arow + ks * 32 + quad * 8);
#pragma unroll
  for (int i = 0; i < 4; ++i) acc[i] = (f32x4){0, 0, 0, 0};
#pragma unroll
  for (int ntl = 0; ntl < 4; ++ntl) {
    const int n = (nh * 4 + ntl) * 16 + col;
#pragma unroll
    for (int ks = 0; ks < 4; ++ks) {
      bf16x8 bb = *(const bf16x8*)(Wg2 + n * 128 + ks * 32 + quad * 8);
      acc[ntl] = __builtin_amdgcn_mfma_f32_16x16x32_bf16(A[ks], bb, acc[ntl], 0, 0, 0);
    }
  }
#pragma unroll
  for (int ntl = 0; ntl < 4; ++ntl) {
    const int n = (nh * 4 + ntl) * 16 + col;
    ushort4 pk;
    pk.x = (unsigned short)f2bf(acc[ntl][0]);
    pk.y = (unsigned short)f2bf(acc[ntl][1]);
    pk.z = (unsigned short)f2bf(acc[ntl][2]);
    pk.w = (unsigned short)f2bf(acc[ntl][3]);
    *(ushort4*)(sT + n * 72 + rg * 16 + quad * 4) = pk;
  }
  __syncthreads();

  // ---- AGG2 ----
#pragma unroll
  for (int i = 0; i < 4; ++i) acc[i] = (f32x4){0, 0, 0, 0};
#pragma unroll
  for (int ntl = 0; ntl < 4; ++ntl) {
    const int n = (nh * 4 + ntl) * 16 + col;
#pragma unroll
    for (int ks = 0; ks < 2; ++ks) {
      bf16x8 bb = *(const bf16x8*)(sT + n * 72 + ks * 32 + quad * 8);
      acc[ntl] = __builtin_amdgcn_mfma_f32_16x16x32_bf16(Ah[ks], bb, acc[ntl], 0, 0, 0);
    }
  }
#pragma unroll
  for (int ntl = 0; ntl < 4; ++ntl) {
    const int n = (nh * 4 + ntl) * 16 + col;
    const float bv = b_g2[n];
#pragma unroll
    for (int reg = 0; reg < 4; ++reg)
      sAct[crow0 + reg * 136 + n] = f2bf(fmaxf(acc[ntl][reg] + bv, 0.0f));
  }
  __syncthreads();

  // ---- HEAD ----
  if (tid < 320) {
    const int j = tid / 5, o = tid - 5 * j;
    float a0 = 0.0f;
#pragma unroll
    for (int k8 = 0; k8 < 16; ++k8) {
      union { bf16x8 v; unsigned short u[8]; } h;
      h.v = *(const bf16x8*)(sAct + j * 136 + k8 * 8);
#pragma unroll
      for (int jj = 0; jj < 8; ++jj)
        a0 = fmaf(bf2f(h.u[jj]), sWo[o * 128 + k8 * 8 + jj], a0);
    }
    out[(b * 64 + j) * 5 + o] = a0 + b_o[o];
  }
}

extern "C" void kernel_launch(void* const* d_in, const int* in_sizes, int n_in,
                              void* d_out, int out_size, void* d_ws, size_t ws_size,
                              hipStream_t stream) {
  const float* x    = (const float*)d_in[0];
  const float* gso  = (const float*)d_in[1];
  const float* w_c1 = (const float*)d_in[2];
  const float* b_c1 = (const float*)d_in[3];
  const float* g_b1 = (const float*)d_in[4];
  const float* e_b1 = (const float*)d_in[5];
  const float* w_c2 = (const float*)d_in[6];
  const float* b_c2 = (const float*)d_in[7];
  const float* g_b2 = (const float*)d_in[8];
  const float* e_b2 = (const float*)d_in[9];
  const float* w_c3 = (const float*)d_in[10];
  const float* b_c3 = (const float*)d_in[11];
  const float* g_b3 = (const float*)d_in[12];
  const float* e_b3 = (const float*)d_in[13];
  const float* w_fc = (const float*)d_in[14];
  const float* b_fc = (const float*)d_in[15];
  const float* w_g1 = (const float*)d_in[16];
  const float* b_g1 = (const float*)d_in[17];
  const float* w_g2 = (const float*)d_in[18];
  const float* b_g2 = (const float*)d_in[19];
  const float* w_o  = (const float*)d_in[20];
  const float* b_o  = (const float*)d_in[21];
  float* out = (float*)d_out;
  char* ws = (char*)d_ws;

  // workspace layout (bytes) — NO ALIASING, total ~4.5 MB
  short* c3  = (short*)(ws + 0);         //  4,194,304
  short* B1  = (short*)(ws + 4194304);   //  4,096   (fragment order)
  short* B2  = (short*)(ws + 4198400);   //  36,864  (fragment order)
  short* B3  = (short*)(ws + 4235264);   //  147,456 (fragment order)
  short* Wfc = (short*)(ws + 4382720);   //  32,768
  short* Wg1 = (short*)(ws + 4415488);   //  32,768
  short* Wg2 = (short*)(ws + 4448256);   //  32,768

  pack_all<<<560, 256, 0, stream>>>(w_c1, w_c2, w_c3, w_fc, w_g1, w_g2,
                                    B1, B2, B3, Wfc, Wg1, Wg2);
  conv_all<<<1024, 256, 0, stream>>>(x, B1, B2, B3, b_c1, g_b1, e_b1,
                                     b_c2, g_b2, e_b2, b_c3, g_b3, e_b3, c3);
  fused_dense<<<256, 512, 0, stream>>>(c3, gso, Wfc, Wg1, Wg2, b_fc, b_g1,
                                       b_g2, w_o, b_o, out);
}